// Round 20
// baseline (139.580 us; speedup 1.0000x reference)
//
#include <hip/hip_runtime.h>
#include <hip/hip_bf16.h>
#include <cstdint>
#include <cstddef>

#define NROWS 8192
#define KDIM  2048
#define ODIM  1000
#define NSUB  8
#define OPAD  1024   // padded output dim for Wt

#define BM 160
#define BN 256
#define BK 64
#define MT_MAX 8                 // 8 x 160 = 1280 rows/subject covered
#define SLOTB (BN * BK)          // 16384 elems (32KB) -- B-only slots

typedef __attribute__((ext_vector_type(4))) float f32x4;
typedef __attribute__((ext_vector_type(8))) short short8v;
typedef __attribute__((ext_vector_type(4))) unsigned short u16x4;
typedef __attribute__((ext_vector_type(4))) int int4v;

__device__ __forceinline__ unsigned short f2bf(float f){
  unsigned u = __builtin_bit_cast(unsigned, f);
  unsigned r = (u + 0x7FFFu + ((u >> 16) & 1u)) >> 16;  // RNE
  return (unsigned short)r;
}

__device__ __forceinline__ void gload16(const void* g, void* l){
  __builtin_amdgcn_global_load_lds(
      (const __attribute__((address_space(1))) void*)g,
      (__attribute__((address_space(3))) void*)l, 16, 0, 0);
}

// ---------------- K1: fused build_perm (blocks 0-7) + streaming cvt (blocks 8+) ----------------
__global__ __launch_bounds__(256) void perm_cvt(const int* __restrict__ sid,
                                                int* __restrict__ counts,
                                                int* __restrict__ offsets,
                                                int* __restrict__ perm,
                                                const float* __restrict__ x,
                                                unsigned short* __restrict__ xb){
  int b = blockIdx.x;
  int t = threadIdx.x;

  if (b >= 8){
    size_t base = (size_t)(b - 8) * 8192 + (size_t)t * 8;
    #pragma unroll
    for (int c = 0; c < 4; c++){
      size_t f = base + (size_t)c * 2048;
      f32x4 v0 = *(const f32x4*)(x + f);
      f32x4 v1 = *(const f32x4*)(x + f + 4);
      short8v o;
      o[0] = (short)f2bf(v0[0]); o[1] = (short)f2bf(v0[1]);
      o[2] = (short)f2bf(v0[2]); o[3] = (short)f2bf(v0[3]);
      o[4] = (short)f2bf(v1[0]); o[5] = (short)f2bf(v1[1]);
      o[6] = (short)f2bf(v1[2]); o[7] = (short)f2bf(v1[3]);
      *(short8v*)(xb + f) = o;
    }
    return;
  }

  int s = b;
  __shared__ int shs[NROWS];
  __shared__ int red_lt[4], red_eq[4], wsum[4];
  __shared__ int sh_base;

  int lane = t & 63, wv = t >> 6;
  int c_lt = 0, c_eq = 0;
  const int4v* sv = (const int4v*)sid;
  #pragma unroll
  for (int i = 0; i < NROWS / 4 / 256; i++){
    int idx = i * 256 + t;
    int4v v = sv[idx];
    *(int4v*)&shs[idx * 4] = v;
    #pragma unroll
    for (int e = 0; e < 4; e++){ c_lt += (v[e] < s); c_eq += (v[e] == s); }
  }
  #pragma unroll
  for (int d = 32; d >= 1; d >>= 1){
    c_lt += __shfl_xor(c_lt, d);
    c_eq += __shfl_xor(c_eq, d);
  }
  if (lane == 0){ red_lt[wv] = c_lt; red_eq[wv] = c_eq; }
  __syncthreads();
  if (t == 0){
    int lt = red_lt[0] + red_lt[1] + red_lt[2] + red_lt[3];
    int eq = red_eq[0] + red_eq[1] + red_eq[2] + red_eq[3];
    offsets[s] = lt;
    counts[s]  = eq;
    sh_base = lt;
  }
  __syncthreads();
  int base = sh_base;

  for (int c0 = 0; c0 < NROWS; c0 += 256){
    int v = shs[c0 + t];
    bool eq = (v == s);
    unsigned long long m = __ballot(eq);
    int rk = __popcll(m & ((1ull << lane) - 1ull));
    int wc = __popcll(m);
    if (lane == 0) wsum[wv] = wc;
    __syncthreads();
    int woff = 0;
    #pragma unroll
    for (int w = 0; w < 4; w++) if (w < wv) woff += wsum[w];
    int tot = wsum[0] + wsum[1] + wsum[2] + wsum[3];
    if (eq) perm[base + woff + rk] = c0 + t;
    base += tot;
    __syncthreads();
  }
}

// ---------------- K2: transpose + cvt W[s][k][o] -> Wt[s][o][k] bf16 ----------------
__global__ __launch_bounds__(256) void transpose_w(const float* __restrict__ W,
                                                   unsigned short* __restrict__ Wt){
  __shared__ float tile[64][65];
  int b = blockIdx.x;
  int t = threadIdx.x;
  int s  = b >> 9;
  int kt = (b >> 4) & 31;
  int ot = b & 15;
  int k0 = kt * 64, o0 = ot * 64;

  int kr  = t >> 4;
  int ol4 = (t & 15) * 4;
  bool lval = (o0 + ol4) < ODIM;

  const float* src = W + ((size_t)s * KDIM + k0) * ODIM + o0;
  #pragma unroll
  for (int it = 0; it < 4; it++){
    int k = kr + it * 16;
    f32x4 v = lval ? *(const f32x4*)(src + (size_t)k * ODIM + ol4)
                   : f32x4{0.f, 0.f, 0.f, 0.f};
    tile[k][ol4 + 0] = v[0]; tile[k][ol4 + 1] = v[1];
    tile[k][ol4 + 2] = v[2]; tile[k][ol4 + 3] = v[3];
  }
  __syncthreads();

  int j8   = (t & 7) * 8;
  int orow = t >> 3;
  unsigned short* dst = Wt + ((size_t)(s * OPAD + o0)) * KDIM + k0;
  #pragma unroll
  for (int it = 0; it < 2; it++){
    int o = orow + it * 32;
    bool oval = (o0 + o) < ODIM;
    short8v w;
    #pragma unroll
    for (int j = 0; j < 8; j++)
      w[j] = oval ? (short)f2bf(tile[j8 + j][o]) : (short)0;
    *(short8v*)(dst + (size_t)o * KDIM + j8) = w;
  }
}

// ---------------- K3: grouped bf16 MFMA GEMM, 160x256, A-direct-to-register ----------------
// A-fragments loaded global->VGPR (inline asm, X/Y dbuf, 1 tile ahead) --
// NO LDS traffic for A (cuts per-tile LDS reads 144KB -> 64KB per CU).
// B: 3-slot LDS ring (96KB), uniform 4 gload_lds/thread, counted vmcnt(4)
// (A(t+1) issued BEFORE B(t+2) so the FIFO wait covers both), 1 barrier +
// 1 lgkm per K-tile (R18 skeleton). Subject->XCD mapping, direct stores.
__global__ __launch_bounds__(512, 1) void gemm_bf16(
    const unsigned short* __restrict__ xb,   // [8192][2048] bf16 (orig order)
    const unsigned short* __restrict__ Wt,   // [8][1024][2048] bf16
    const int* __restrict__ counts,
    const int* __restrict__ offsets,
    const int* __restrict__ perm,
    const float* __restrict__ bias,          // [8][1000]
    float* __restrict__ out)                 // [8192][1000]
{
  int b  = blockIdx.x;
  int s  = b & 7;                 // subject == XCD
  int r  = b >> 3;
  int nt = r & 3;                 // 0..3
  int mt = r >> 2;                // 0..7
  int cnt = counts[s];
  int loc0 = mt * BM;
  if (loc0 >= cnt) return;
  int row0 = offsets[s] + loc0;
  int cnt_loc = cnt - loc0;

  __shared__ unsigned short L[3 * SLOTB];    // 3 x 32KB B-ring

  int t = threadIdx.x;
  int lane = t & 63;
  int wave = t >> 6;              // 0..7

  int wm = (wave >> 2) * 80;      // 2M x 4N waves; wave-tile 80x64
  int wn = (wave & 3) << 6;
  int frow = lane & 15, fk = lane >> 4;
  int axor = frow & 7;

  // ---- A-direct: per-lane perm'd row addresses (frag layout: row=frow, kchunk=fk)
  unsigned voffA[5];
  {
    int prowA[5];
    #pragma unroll
    for (int mi = 0; mi < 5; mi++){
      int rrow = wm + mi * 16 + frow;                    // 0..159
      int pidx = row0 + rrow; if (pidx > NROWS - 1) pidx = NROWS - 1;
      prowA[mi] = perm[pidx];
    }
    #pragma unroll
    for (int mi = 0; mi < 5; mi++)
      voffA[mi] = (unsigned)prowA[mi] * (KDIM * 2) + (unsigned)fk * 16;  // bytes
  }
  asm volatile("s_waitcnt vmcnt(0)" ::: "memory");       // queue empty for ledger
  __builtin_amdgcn_sched_barrier(0);

  // ---- B staging: uniform 4 chunks/thread, R4-verified XOR swizzle
  int srck = (((t & 7) ^ ((t >> 3) & 7)) << 3);
  size_t gB[4]; unsigned loB[4];
  #pragma unroll
  for (int j = 0; j < 4; j++){
    int row = (t >> 3) + 64 * j;                         // 0..255
    gB[j]  = ((size_t)(s * OPAD + nt * BN + row)) * KDIM + srck;
    loB[j] = (unsigned)(((j * 512 + t)) * 8);            // elems; = wavebase + lane*8
  }

  f32x4 acc[5][4];
  #pragma unroll
  for (int i = 0; i < 5; i++)
    #pragma unroll
    for (int j = 0; j < 4; j++)
      #pragma unroll
      for (int e = 0; e < 4; e++) acc[i][j][e] = 0.f;

  short8v X[5][2], Y[5][2];       // A fragment sets (static indexing only)

#define GLA(dst, voff, IMM) \
  asm volatile("global_load_dwordx4 %0, %1, %2 offset:" IMM \
               : "=v"(dst) : "v"(voff), "s"(xb))

// load A frags for next tile into set P; advance voffA by one K-tile (128B)
#define LDA(P) do { \
    GLA(P[0][0], voffA[0], "0"); GLA(P[0][1], voffA[0], "64"); \
    GLA(P[1][0], voffA[1], "0"); GLA(P[1][1], voffA[1], "64"); \
    GLA(P[2][0], voffA[2], "0"); GLA(P[2][1], voffA[2], "64"); \
    GLA(P[3][0], voffA[3], "0"); GLA(P[3][1], voffA[3], "64"); \
    GLA(P[4][0], voffA[4], "0"); GLA(P[4][1], voffA[4], "64"); \
    _Pragma("unroll") \
    for (int mi = 0; mi < 5; mi++) voffA[mi] += 128; \
    __builtin_amdgcn_sched_barrier(0); \
  } while (0)

#define STAGEB(sl, koff) do { \
    unsigned short* Ls = &L[(sl) * SLOTB]; \
    gload16(Wt + gB[0] + (koff), (void*)(Ls + loB[0])); \
    gload16(Wt + gB[1] + (koff), (void*)(Ls + loB[1])); \
    gload16(Wt + gB[2] + (koff), (void*)(Ls + loB[2])); \
    gload16(Wt + gB[3] + (koff), (void*)(Ls + loB[3])); \
    __builtin_amdgcn_sched_barrier(0); \
  } while (0)

#define VMN() do { \
    asm volatile("s_waitcnt vmcnt(4)" ::: "memory"); \
    __builtin_amdgcn_sched_barrier(0); \
  } while (0)
#define VM0() do { \
    asm volatile("s_waitcnt vmcnt(0)" ::: "memory"); \
    __builtin_amdgcn_sched_barrier(0); \
  } while (0)

#define BOFF(ni, ks) (((wn + ((ni) << 4) + frow) << 6) + ((((ks) * 4 + fk) ^ axor) << 3))
#define MF(mi, ni, av, bv) acc[mi][ni] = __builtin_amdgcn_mfma_f32_16x16x32_bf16(av, bv, acc[mi][ni], 0, 0, 0)

#define MFMA40(P, BF) do { \
    __builtin_amdgcn_s_setprio(1); \
    _Pragma("unroll") \
    for (int ks = 0; ks < 2; ks++) \
      _Pragma("unroll") \
      for (int mi = 0; mi < 5; mi++) \
        _Pragma("unroll") \
        for (int ni = 0; ni < 4; ni++) \
          MF(mi, ni, P[mi][ks], BF[ni][ks]); \
    __builtin_amdgcn_s_setprio(0); \
  } while (0)

// one K-tile: {8 ds_read(B) | LDA(next) | STAGEB(t+2)} -> lgkm -> 40 MFMA -> ENDW -> barrier
#define TILE(sl, CUR, LDAP, STG, ENDW) do { \
    const unsigned short* Lb = &L[(sl) * SLOTB]; \
    short8v bf[4][2]; \
    _Pragma("unroll") \
    for (int ks = 0; ks < 2; ks++) \
      _Pragma("unroll") \
      for (int ni = 0; ni < 4; ni++) \
        bf[ni][ks] = *(const short8v*)&Lb[BOFF(ni, ks)]; \
    __builtin_amdgcn_sched_barrier(0); \
    LDAP; \
    STG; \
    asm volatile("s_waitcnt lgkmcnt(0)" ::: "memory"); \
    __builtin_amdgcn_sched_barrier(0); \
    MFMA40(CUR, bf); \
    ENDW; \
    __builtin_amdgcn_s_barrier(); \
  } while (0)

  // prologue: A(0)->X, B(0)->slot0, B(1)->slot1; wait X+B(0), leave B(1)
  LDA(X);
  STAGEB(0, 0);
  STAGEB(1, BK);
  asm volatile("s_waitcnt vmcnt(4)" ::: "memory");
  __builtin_amdgcn_sched_barrier(0);
  __builtin_amdgcn_s_barrier();

  // main loop: tiles 0..29 (5 iters x 6 tiles; slots 0,1,2 ring; X/Y alternate)
  for (int i = 0; i < 5; ++i){
    int kb = i * 6 * BK;
    TILE(0, X, LDA(Y), STAGEB(2, kb + 2 * BK), VMN());
    TILE(1, Y, LDA(X), STAGEB(0, kb + 3 * BK), VMN());
    TILE(2, X, LDA(Y), STAGEB(1, kb + 4 * BK), VMN());
    TILE(0, Y, LDA(X), STAGEB(2, kb + 5 * BK), VMN());
    TILE(1, X, LDA(Y), STAGEB(0, kb + 6 * BK), VMN());
    TILE(2, Y, LDA(X), STAGEB(1, kb + 7 * BK), VMN());
  }
  // tail: tile 30 (slot 0, X; load A(31); drain all), tile 31 (slot 1, Y)
  TILE(0, X, LDA(Y), , VM0());
  TILE(1, Y, , , );

  // epilogue: C/D layout col=lane&15, row=(lane>>4)*4+reg; perm read direct
  float bvn[4]; int ocol[4];
  #pragma unroll
  for (int ni = 0; ni < 4; ni++){
    int o = nt * BN + wn + (ni << 4) + frow;
    ocol[ni] = o;
    bvn[ni] = (o < ODIM) ? bias[s * ODIM + o] : 0.f;
  }
  #pragma unroll
  for (int mi = 0; mi < 5; mi++){
    int rbase = wm + (mi << 4) + (fk << 2);
    #pragma unroll
    for (int jj = 0; jj < 4; jj++){
      int rr = rbase + jj;
      if (rr < cnt_loc){
        int orow = perm[row0 + rr];
        #pragma unroll
        for (int ni = 0; ni < 4; ni++){
          if (ocol[ni] < ODIM)
            out[(size_t)orow * ODIM + ocol[ni]] = acc[mi][ni][jj] + bvn[ni];
        }
      }
    }
  }
#undef GLA
#undef LDA
#undef STAGEB
#undef VMN
#undef VM0
#undef BOFF
#undef MF
#undef MFMA40
#undef TILE
}

// ---------------- fallback: naive fp32 (only if ws too small) ----------------
__global__ __launch_bounds__(256) void naive_kernel(const float* __restrict__ x,
                                                    const int* __restrict__ sid,
                                                    const float* __restrict__ W,
                                                    const float* __restrict__ bias,
                                                    float* __restrict__ out){
  __shared__ float xr[KDIM];
  int row = blockIdx.x;
  int s = sid[row];
  for (int i = threadIdx.x; i < KDIM; i += 256) xr[i] = x[(size_t)row * KDIM + i];
  __syncthreads();
  int o = blockIdx.y * 256 + threadIdx.x;
  if (o >= ODIM) return;
  const float* w = W + (size_t)s * KDIM * ODIM + o;
  float acc = bias[s * ODIM + o];
  for (int k = 0; k < KDIM; k++) acc = fmaf(xr[k], w[(size_t)k * ODIM], acc);
  out[(size_t)row * ODIM + o] = acc;
}

extern "C" void kernel_launch(void* const* d_in, const int* in_sizes, int n_in,
                              void* d_out, int out_size, void* d_ws, size_t ws_size,
                              hipStream_t stream) {
  const float* x    = (const float*)d_in[0];
  const int*   sid  = (const int*)d_in[1];
  const float* W    = (const float*)d_in[2];
  const float* bias = (const float*)d_in[3];
  float* out = (float*)d_out;

  const size_t XB_BYTES = (size_t)NROWS * KDIM * 2;
  const size_t WT_BYTES = (size_t)NSUB * OPAD * KDIM * 2;
  const size_t need = 64 + (size_t)NROWS * 4 + XB_BYTES + WT_BYTES;

  if (ws_size < need){
    naive_kernel<<<dim3(NROWS, 4), 256, 0, stream>>>(x, sid, W, bias, out);
    return;
  }

  char* w = (char*)d_ws;
  int* counts  = (int*)w;                      // 8 ints
  int* offsets = counts + 8;                   // 8 ints
  int* perm    = (int*)(w + 64);               // 8192 ints
  unsigned short* xb = (unsigned short*)(w + 64 + (size_t)NROWS * 4);
  unsigned short* Wt = xb + (size_t)NROWS * KDIM;

  perm_cvt    <<<8 + 2048, 256, 0, stream>>>(sid, counts, offsets, perm, x, xb);
  transpose_w <<<4096, 256, 0, stream>>>(W, Wt);
  gemm_bf16   <<<NSUB * 4 * MT_MAX, 512, 0, stream>>>(xb, Wt, counts, offsets, perm, bias, out);
}

// Round 21
// 85.550 us; speedup vs baseline: 1.6316x; 1.6316x over previous
//
#include <hip/hip_runtime.h>
#include <hip/hip_bf16.h>
#include <cstdint>
#include <cstddef>

#define NROWS 8192
#define KDIM  2048
#define ODIM  1000
#define NSUB  8
#define OPAD  1024   // padded output dim for Wt

#define BM 160
#define BN 256
#define BK 64
#define MT_MAX 8                 // 8 x 160 = 1280 rows/subject covered
#define ASLOT (BM * BK)          // 10240 elems (20KB)
#define SLOT  ((BM + BN) * BK)   // 26624 elems (53248B)

typedef __attribute__((ext_vector_type(4))) float f32x4;
typedef __attribute__((ext_vector_type(8))) short short8v;
typedef __attribute__((ext_vector_type(4))) unsigned short u16x4;
typedef __attribute__((ext_vector_type(4))) int int4v;

__device__ __forceinline__ unsigned short f2bf(float f){
  unsigned u = __builtin_bit_cast(unsigned, f);
  unsigned r = (u + 0x7FFFu + ((u >> 16) & 1u)) >> 16;  // RNE
  return (unsigned short)r;
}

__device__ __forceinline__ void gload16(const void* g, void* l){
  __builtin_amdgcn_global_load_lds(
      (const __attribute__((address_space(1))) void*)g,
      (__attribute__((address_space(3))) void*)l, 16, 0, 0);
}

// ---------------- K1: fused build_perm (blocks 0-7) + streaming cvt (blocks 8+) ----------------
__global__ __launch_bounds__(256) void perm_cvt(const int* __restrict__ sid,
                                                int* __restrict__ counts,
                                                int* __restrict__ offsets,
                                                int* __restrict__ perm,
                                                const float* __restrict__ x,
                                                unsigned short* __restrict__ xb){
  int b = blockIdx.x;
  int t = threadIdx.x;

  if (b >= 8){
    size_t base = (size_t)(b - 8) * 8192 + (size_t)t * 8;
    #pragma unroll
    for (int c = 0; c < 4; c++){
      size_t f = base + (size_t)c * 2048;
      f32x4 v0 = *(const f32x4*)(x + f);
      f32x4 v1 = *(const f32x4*)(x + f + 4);
      short8v o;
      o[0] = (short)f2bf(v0[0]); o[1] = (short)f2bf(v0[1]);
      o[2] = (short)f2bf(v0[2]); o[3] = (short)f2bf(v0[3]);
      o[4] = (short)f2bf(v1[0]); o[5] = (short)f2bf(v1[1]);
      o[6] = (short)f2bf(v1[2]); o[7] = (short)f2bf(v1[3]);
      *(short8v*)(xb + f) = o;
    }
    return;
  }

  int s = b;
  __shared__ int shs[NROWS];
  __shared__ int red_lt[4], red_eq[4], wsum[4];
  __shared__ int sh_base;

  int lane = t & 63, wv = t >> 6;
  int c_lt = 0, c_eq = 0;
  const int4v* sv = (const int4v*)sid;
  #pragma unroll
  for (int i = 0; i < NROWS / 4 / 256; i++){
    int idx = i * 256 + t;
    int4v v = sv[idx];
    *(int4v*)&shs[idx * 4] = v;
    #pragma unroll
    for (int e = 0; e < 4; e++){ c_lt += (v[e] < s); c_eq += (v[e] == s); }
  }
  #pragma unroll
  for (int d = 32; d >= 1; d >>= 1){
    c_lt += __shfl_xor(c_lt, d);
    c_eq += __shfl_xor(c_eq, d);
  }
  if (lane == 0){ red_lt[wv] = c_lt; red_eq[wv] = c_eq; }
  __syncthreads();
  if (t == 0){
    int lt = red_lt[0] + red_lt[1] + red_lt[2] + red_lt[3];
    int eq = red_eq[0] + red_eq[1] + red_eq[2] + red_eq[3];
    offsets[s] = lt;
    counts[s]  = eq;
    sh_base = lt;
  }
  __syncthreads();
  int base = sh_base;

  for (int c0 = 0; c0 < NROWS; c0 += 256){
    int v = shs[c0 + t];
    bool eq = (v == s);
    unsigned long long m = __ballot(eq);
    int rk = __popcll(m & ((1ull << lane) - 1ull));
    int wc = __popcll(m);
    if (lane == 0) wsum[wv] = wc;
    __syncthreads();
    int woff = 0;
    #pragma unroll
    for (int w = 0; w < 4; w++) if (w < wv) woff += wsum[w];
    int tot = wsum[0] + wsum[1] + wsum[2] + wsum[3];
    if (eq) perm[base + woff + rk] = c0 + t;
    base += tot;
    __syncthreads();
  }
}

// ---------------- K2: transpose + cvt W[s][k][o] -> Wt[s][o][k] bf16 ----------------
__global__ __launch_bounds__(256) void transpose_w(const float* __restrict__ W,
                                                   unsigned short* __restrict__ Wt){
  __shared__ float tile[64][65];
  int b = blockIdx.x;
  int t = threadIdx.x;
  int s  = b >> 9;
  int kt = (b >> 4) & 31;
  int ot = b & 15;
  int k0 = kt * 64, o0 = ot * 64;

  int kr  = t >> 4;
  int ol4 = (t & 15) * 4;
  bool lval = (o0 + ol4) < ODIM;

  const float* src = W + ((size_t)s * KDIM + k0) * ODIM + o0;
  #pragma unroll
  for (int it = 0; it < 4; it++){
    int k = kr + it * 16;
    f32x4 v = lval ? *(const f32x4*)(src + (size_t)k * ODIM + ol4)
                   : f32x4{0.f, 0.f, 0.f, 0.f};
    tile[k][ol4 + 0] = v[0]; tile[k][ol4 + 1] = v[1];
    tile[k][ol4 + 2] = v[2]; tile[k][ol4 + 3] = v[3];
  }
  __syncthreads();

  int j8   = (t & 7) * 8;
  int orow = t >> 3;
  unsigned short* dst = Wt + ((size_t)(s * OPAD + o0)) * KDIM + k0;
  #pragma unroll
  for (int it = 0; it < 2; it++){
    int o = orow + it * 32;
    bool oval = (o0 + o) < ODIM;
    short8v w;
    #pragma unroll
    for (int j = 0; j < 8; j++)
      w[j] = oval ? (short)f2bf(tile[j8 + j][o]) : (short)0;
    *(short8v*)(dst + (size_t)o * KDIM + j8) = w;
  }
}

// ---------------- K3: grouped bf16 MFMA GEMM, 160x256, 8 waves, 3-slot ring ----------------
// R18 skeleton (1 barrier/tile, counted VMN(7/6) never draining) with the
// tile body COMPILER-SCHEDULED: issue all 18 ds_reads + staging, then one
// setprio'd 40-MFMA cluster with NO manual lgkm / sched_barrier -- the
// compiler emits fine-grained counted lgkmcnt per register dep, so read
// returns overlap MFMA issue (kills the intra-tile lgkm convoy).
__global__ __launch_bounds__(512, 1) void gemm_bf16(
    const unsigned short* __restrict__ xb,   // [8192][2048] bf16 (orig order)
    const unsigned short* __restrict__ Wt,   // [8][1024][2048] bf16
    const int* __restrict__ counts,
    const int* __restrict__ offsets,
    const int* __restrict__ perm,
    const float* __restrict__ bias,          // [8][1000]
    float* __restrict__ out)                 // [8192][1000]
{
  int b  = blockIdx.x;
  int s  = b & 7;                 // subject == XCD
  int r  = b >> 3;
  int nt = r & 3;                 // 0..3
  int mt = r >> 2;                // 0..7
  int cnt = counts[s];
  int loc0 = mt * BM;
  if (loc0 >= cnt) return;
  int row0 = offsets[s] + loc0;
  int cnt_loc = cnt - loc0;

  __shared__ unsigned short L[3 * SLOT];     // 3 x 53248B ring
  __shared__ int permL[BM];

  int t = threadIdx.x;
  int lane = t & 63;
  int wave = t >> 6;              // 0..7

  int wm = (wave >> 2) * 80;      // 2M x 4N waves; wave-tile 80x64
  int wn = (wave & 3) << 6;
  int frow = lane & 15, fk = lane >> 4;
  int axor = frow & 7;

  int srck = (((lane & 7) ^ ((lane >> 3) & 7)) << 3);

  // prologue perm fetches: per-lane gathered A-rows + permL for epilogue
  int prow[5];
  if (wave < 4){
    #pragma unroll
    for (int i = 0; i < 5; i++){
      int row = ((wave * 5 + i) << 3) + (lane >> 3);      // 0..159
      int pidx = row0 + row; if (pidx > NROWS - 1) pidx = NROWS - 1;
      prow[i] = perm[pidx];
    }
  }
  {
    int pr = t;
    if (pr >= 320) pr -= 320;
    if (pr >= 160) pr -= 160;               // pr in [0,160)
    int pidx = row0 + pr; if (pidx > NROWS - 1) pidx = NROWS - 1;
    int pl = perm[pidx];
    asm volatile("s_waitcnt vmcnt(0)" ::: "memory");      // drain prologue
    __builtin_amdgcn_sched_barrier(0);
    permL[pr] = pl;
  }

  size_t gA[5]; unsigned loA[5];
  size_t gB[6]; unsigned loB[6];
  if (wave < 4){
    #pragma unroll
    for (int i = 0; i < 5; i++){
      int ca = wave * 5 + i;                 // 0..19
      gA[i]  = (size_t)prow[i] * KDIM + srck;
      loA[i] = (unsigned)((ca << 9) + (lane << 3));
    }
    #pragma unroll
    for (int j = 0; j < 2; j++){
      int cb  = wave * 2 + j;                // 0..7
      int row = (cb << 3) + (lane >> 3);
      gB[j]  = ((size_t)(s * OPAD + nt * BN + row)) * KDIM + srck;
      loB[j] = (unsigned)(ASLOT + (cb << 9) + (lane << 3));
    }
  } else {
    #pragma unroll
    for (int j = 0; j < 6; j++){
      int cb  = 8 + (wave - 4) * 6 + j;      // 8..31
      int row = (cb << 3) + (lane >> 3);
      gB[j]  = ((size_t)(s * OPAD + nt * BN + row)) * KDIM + srck;
      loB[j] = (unsigned)(ASLOT + (cb << 9) + (lane << 3));
    }
  }

  f32x4 acc[5][4];
  #pragma unroll
  for (int i = 0; i < 5; i++)
    #pragma unroll
    for (int j = 0; j < 4; j++)
      #pragma unroll
      for (int e = 0; e < 4; e++) acc[i][j][e] = 0.f;

#define STAGE_FULL(sl, koff) do { \
    unsigned short* Ls = &L[(sl) * SLOT]; \
    if (wave < 4){ \
      gload16(xb + gA[0] + (koff), (void*)(Ls + loA[0])); \
      gload16(xb + gA[1] + (koff), (void*)(Ls + loA[1])); \
      gload16(xb + gA[2] + (koff), (void*)(Ls + loA[2])); \
      gload16(xb + gA[3] + (koff), (void*)(Ls + loA[3])); \
      gload16(xb + gA[4] + (koff), (void*)(Ls + loA[4])); \
      gload16(Wt + gB[0] + (koff), (void*)(Ls + loB[0])); \
      gload16(Wt + gB[1] + (koff), (void*)(Ls + loB[1])); \
    } else { \
      gload16(Wt + gB[0] + (koff), (void*)(Ls + loB[0])); \
      gload16(Wt + gB[1] + (koff), (void*)(Ls + loB[1])); \
      gload16(Wt + gB[2] + (koff), (void*)(Ls + loB[2])); \
      gload16(Wt + gB[3] + (koff), (void*)(Ls + loB[3])); \
      gload16(Wt + gB[4] + (koff), (void*)(Ls + loB[4])); \
      gload16(Wt + gB[5] + (koff), (void*)(Ls + loB[5])); \
    } \
  } while (0)

#define VMN() do { \
    if (wave < 4) asm volatile("s_waitcnt vmcnt(7)" ::: "memory"); \
    else          asm volatile("s_waitcnt vmcnt(6)" ::: "memory"); \
    __builtin_amdgcn_sched_barrier(0); \
  } while (0)
#define VM0() do { \
    asm volatile("s_waitcnt vmcnt(0)" ::: "memory"); \
    __builtin_amdgcn_sched_barrier(0); \
  } while (0)

#define AOFF(mi, ks) (((wm + ((mi) << 4) + frow) << 6) + ((((ks) * 4 + fk) ^ axor) << 3))
#define BOFF(ni, ks) (ASLOT + ((wn + ((ni) << 4) + frow) << 6) + ((((ks) * 4 + fk) ^ axor) << 3))
#define MF(mi, ni, av, bv) acc[mi][ni] = __builtin_amdgcn_mfma_f32_16x16x32_bf16(av, bv, acc[mi][ni], 0, 0, 0)

// one K-tile: all 18 ds_reads + staging issued, then one 40-MFMA cluster.
// NO manual lgkm: compiler inserts minimal counted lgkmcnt per register
// dep, interleaving read returns with MFMA issue.
#define TILE(sl, STG, ENDW) do { \
    const unsigned short* Lb = &L[(sl) * SLOT]; \
    short8v xa0 = *(const short8v*)&Lb[AOFF(0, 0)]; \
    short8v xa1 = *(const short8v*)&Lb[AOFF(1, 0)]; \
    short8v xa2 = *(const short8v*)&Lb[AOFF(2, 0)]; \
    short8v xa3 = *(const short8v*)&Lb[AOFF(3, 0)]; \
    short8v xa4 = *(const short8v*)&Lb[AOFF(4, 0)]; \
    short8v xb0 = *(const short8v*)&Lb[BOFF(0, 0)]; \
    short8v xb1 = *(const short8v*)&Lb[BOFF(1, 0)]; \
    short8v xb2 = *(const short8v*)&Lb[BOFF(2, 0)]; \
    short8v xb3 = *(const short8v*)&Lb[BOFF(3, 0)]; \
    short8v ya0 = *(const short8v*)&Lb[AOFF(0, 1)]; \
    short8v ya1 = *(const short8v*)&Lb[AOFF(1, 1)]; \
    short8v ya2 = *(const short8v*)&Lb[AOFF(2, 1)]; \
    short8v ya3 = *(const short8v*)&Lb[AOFF(3, 1)]; \
    short8v ya4 = *(const short8v*)&Lb[AOFF(4, 1)]; \
    short8v yb0 = *(const short8v*)&Lb[BOFF(0, 1)]; \
    short8v yb1 = *(const short8v*)&Lb[BOFF(1, 1)]; \
    short8v yb2 = *(const short8v*)&Lb[BOFF(2, 1)]; \
    short8v yb3 = *(const short8v*)&Lb[BOFF(3, 1)]; \
    STG; \
    __builtin_amdgcn_s_setprio(1); \
    MF(0, 0, xa0, xb0); MF(1, 0, xa1, xb0); MF(2, 0, xa2, xb0); MF(3, 0, xa3, xb0); MF(4, 0, xa4, xb0); \
    MF(0, 1, xa0, xb1); MF(1, 1, xa1, xb1); MF(2, 1, xa2, xb1); MF(3, 1, xa3, xb1); MF(4, 1, xa4, xb1); \
    MF(0, 2, xa0, xb2); MF(1, 2, xa1, xb2); MF(2, 2, xa2, xb2); MF(3, 2, xa3, xb2); MF(4, 2, xa4, xb2); \
    MF(0, 3, xa0, xb3); MF(1, 3, xa1, xb3); MF(2, 3, xa2, xb3); MF(3, 3, xa3, xb3); MF(4, 3, xa4, xb3); \
    MF(0, 0, ya0, yb0); MF(1, 0, ya1, yb0); MF(2, 0, ya2, yb0); MF(3, 0, ya3, yb0); MF(4, 0, ya4, yb0); \
    MF(0, 1, ya0, yb1); MF(1, 1, ya1, yb1); MF(2, 1, ya2, yb1); MF(3, 1, ya3, yb1); MF(4, 1, ya4, yb1); \
    MF(0, 2, ya0, yb2); MF(1, 2, ya1, yb2); MF(2, 2, ya2, yb2); MF(3, 2, ya3, yb2); MF(4, 2, ya4, yb2); \
    MF(0, 3, ya0, yb3); MF(1, 3, ya1, yb3); MF(2, 3, ya2, yb3); MF(3, 3, ya3, yb3); MF(4, 3, ya4, yb3); \
    __builtin_amdgcn_s_setprio(0); \
    ENDW; \
    __builtin_amdgcn_s_barrier(); \
  } while (0)

  STAGE_FULL(0, 0);
  STAGE_FULL(1, BK);
  VMN();                                     // drain stage 0, leave stage 1
  __builtin_amdgcn_s_barrier();

  // main loop: tiles 0..29 (10 iters x 3 slots); stage t+2 within tile t
  for (int i = 0; i < 10; ++i){
    int kb = i * 3 * BK;
    TILE(0, STAGE_FULL(2, kb + 2 * BK), VMN());
    TILE(1, STAGE_FULL(0, kb + 3 * BK), VMN());
    TILE(2, STAGE_FULL(1, kb + 4 * BK), VMN());
  }
  // tail: tile 30 drains remaining stage; tile 31 plain
  TILE(0, , VM0());
  TILE(1, , );

  // epilogue: C/D layout col=lane&15, row=(lane>>4)*4+reg
  float bvn[4]; int ocol[4];
  #pragma unroll
  for (int ni = 0; ni < 4; ni++){
    int o = nt * BN + wn + (ni << 4) + frow;
    ocol[ni] = o;
    bvn[ni] = (o < ODIM) ? bias[s * ODIM + o] : 0.f;
  }
  #pragma unroll
  for (int mi = 0; mi < 5; mi++){
    int rbase = wm + (mi << 4) + (fk << 2);
    #pragma unroll
    for (int jj = 0; jj < 4; jj++){
      int rr = rbase + jj;
      if (rr < cnt_loc){
        int orow = permL[rr];
        #pragma unroll
        for (int ni = 0; ni < 4; ni++){
          if (ocol[ni] < ODIM)
            out[(size_t)orow * ODIM + ocol[ni]] = acc[mi][ni][jj] + bvn[ni];
        }
      }
    }
  }
#undef STAGE_FULL
#undef VMN
#undef VM0
#undef AOFF
#undef BOFF
#undef MF
#undef TILE
}

// ---------------- fallback: naive fp32 (only if ws too small) ----------------
__global__ __launch_bounds__(256) void naive_kernel(const float* __restrict__ x,
                                                    const int* __restrict__ sid,
                                                    const float* __restrict__ W,
                                                    const float* __restrict__ bias,
                                                    float* __restrict__ out){
  __shared__ float xr[KDIM];
  int row = blockIdx.x;
  int s = sid[row];
  for (int i = threadIdx.x; i < KDIM; i += 256) xr[i] = x[(size_t)row * KDIM + i];
  __syncthreads();
  int o = blockIdx.y * 256 + threadIdx.x;
  if (o >= ODIM) return;
  const float* w = W + (size_t)s * KDIM * ODIM + o;
  float acc = bias[s * ODIM + o];
  for (int k = 0; k < KDIM; k++) acc = fmaf(xr[k], w[(size_t)k * ODIM], acc);
  out[(size_t)row * ODIM + o] = acc;
}

extern "C" void kernel_launch(void* const* d_in, const int* in_sizes, int n_in,
                              void* d_out, int out_size, void* d_ws, size_t ws_size,
                              hipStream_t stream) {
  const float* x    = (const float*)d_in[0];
  const int*   sid  = (const int*)d_in[1];
  const float* W    = (const float*)d_in[2];
  const float* bias = (const float*)d_in[3];
  float* out = (float*)d_out;

  const size_t XB_BYTES = (size_t)NROWS * KDIM * 2;
  const size_t WT_BYTES = (size_t)NSUB * OPAD * KDIM * 2;
  const size_t need = 64 + (size_t)NROWS * 4 + XB_BYTES + WT_BYTES;

  if (ws_size < need){
    naive_kernel<<<dim3(NROWS, 4), 256, 0, stream>>>(x, sid, W, bias, out);
    return;
  }

  char* w = (char*)d_ws;
  int* counts  = (int*)w;                      // 8 ints
  int* offsets = counts + 8;                   // 8 ints
  int* perm    = (int*)(w + 64);               // 8192 ints
  unsigned short* xb = (unsigned short*)(w + 64 + (size_t)NROWS * 4);
  unsigned short* Wt = xb + (size_t)NROWS * KDIM;

  perm_cvt    <<<8 + 2048, 256, 0, stream>>>(sid, counts, offsets, perm, x, xb);
  transpose_w <<<4096, 256, 0, stream>>>(W, Wt);
  gemm_bf16   <<<NSUB * 4 * MT_MAX, 512, 0, stream>>>(xb, Wt, counts, offsets, perm, bias, out);
}